// Round 5
// baseline (121.047 us; speedup 1.0000x reference)
//
#include <hip/hip_runtime.h>
#include <hip/hip_bf16.h>
#include <math.h>

#define NH 8
#define SDIM 9
#define NSEG 16
#define NATOM 512
#define NEDGE 8192
#define CIN 128
#define CHN 256
#define DH 32
#define FDIM 288            // SDIM*DH
#define EPS 1e-7f
#define SCALE 0.10206207261596577f   // sqrt(32/3)/32

typedef __attribute__((ext_vector_type(8))) short bf16x8;
typedef __attribute__((ext_vector_type(8))) short short8;
typedef __attribute__((ext_vector_type(4))) float f32x4;

// ---------------- block reduce helpers (blockDim.x == 256) ----------------
__device__ inline float blockReduceMax(float v, float* red) {
    #pragma unroll
    for (int off = 32; off; off >>= 1) v = fmaxf(v, __shfl_xor(v, off, 64));
    int lane = threadIdx.x & 63, wid = threadIdx.x >> 6;
    if (lane == 0) red[wid] = v;
    __syncthreads();
    v = fmaxf(fmaxf(red[0], red[1]), fmaxf(red[2], red[3]));
    __syncthreads();
    return v;
}

__device__ inline int lower_bound_batch(const int* __restrict__ b, int val) {
    int lo = 0, hi = NEDGE;
    while (lo < hi) {
        int mid = (lo + hi) >> 1;
        if (b[mid] < val) lo = mid + 1; else hi = mid;
    }
    return lo;
}

// ---------------- K1: fused prep: seg tables (blocks 0..127) + q/k/v projections ----------------
// seg part: E1[h,seg,m] = sum_{e in seg, am=m} env*exp(bias-maxB); E2 same with env^2
// proj part: z=0: q->qhB (H,N,F) pre-scaled; z=1: k->khB; z=2: v->vhT (H,F,N)
__global__ void __launch_bounds__(256) prep_all(const int* __restrict__ batch,
                                                const int* __restrict__ am, const int* __restrict__ emap,
                                                const float* __restrict__ envelope,
                                                const float* __restrict__ attn_bias,
                                                float* __restrict__ E1, float* __restrict__ E2,
                                                const float* __restrict__ q, const float* __restrict__ k,
                                                const float* __restrict__ v,
                                                const float* __restrict__ Wq, const float* __restrict__ Wk,
                                                const float* __restrict__ Wv,
                                                const float* __restrict__ bq, const float* __restrict__ bk,
                                                const float* __restrict__ bv,
                                                __hip_bfloat16* __restrict__ qhB,
                                                __hip_bfloat16* __restrict__ khB,
                                                __hip_bfloat16* __restrict__ vhT) {
    const int bid = blockIdx.x;
    const int tid = threadIdx.x;
    if (bid < NSEG * NH) {
        // ---- segment table part ----
        const int seg = bid & (NSEG - 1), h = bid >> 4;
        __shared__ float e1[NATOM];
        __shared__ float e2[NATOM];
        __shared__ float red[4];
        e1[tid] = 0.f; e1[tid + 256] = 0.f;
        e2[tid] = 0.f; e2[tid + 256] = 0.f;
        const float* bh = attn_bias + (size_t)h * NEDGE;
        float mv = -1e30f;
        for (int e = tid; e < NEDGE; e += 256) mv = fmaxf(mv, bh[e]);
        const float mb = blockReduceMax(mv, red);   // barrier inside covers e1/e2 init
        const int st = lower_bound_batch(batch, seg);
        const int en = lower_bound_batch(batch, seg + 1);
        for (int e = st + tid; e < en; e += 256) {
            int m = am[e], em = emap[e];
            float ev = envelope[em];
            float eb = __expf(bh[em] - mb);
            atomicAdd(&e1[m], ev * eb);
            atomicAdd(&e2[m], ev * ev * eb);
        }
        __syncthreads();
        size_t base = ((size_t)h * NSEG + seg) * NATOM;
        E1[base + tid] = e1[tid]; E1[base + tid + 256] = e1[tid + 256];
        E2[base + tid] = e2[tid]; E2[base + tid + 256] = e2[tid + 256];
        return;
    }
    // ---- projection part ----
    const int idx = bid - NSEG * NH;
    const int z = idx / (64 * SDIM);
    const int rem = idx - z * 64 * SDIM;
    const int s = rem >> 6;
    const int n0 = (rem & 63) * 8;
    const float* x = (z == 0) ? q : (z == 1) ? k : v;
    const float* W = (z == 0) ? Wq : (z == 1) ? Wk : Wv;
    const float* bias = (z == 0) ? bq : (z == 1) ? bk : bv;
    const float scale = (z == 0) ? SCALE : 1.0f;
    const int l = (s == 0) ? 0 : ((s < 4) ? 1 : 2);
    __shared__ float xs[8][CIN];
    for (int i2 = tid; i2 < 8 * CIN; i2 += 256) {
        int r = i2 >> 7, i = i2 & 127;
        xs[r][i] = x[((size_t)(n0 + r) * SDIM + s) * CIN + i];
    }
    __syncthreads();
    const int o = tid;
    const float* Wl = W + (size_t)l * CIN * CHN + o;
    float acc[8] = {0, 0, 0, 0, 0, 0, 0, 0};
    #pragma unroll 4
    for (int i = 0; i < CIN; ++i) {
        float w = Wl[(size_t)i * CHN];
        #pragma unroll
        for (int r = 0; r < 8; ++r) acc[r] += xs[r][i] * w;
    }
    float bb = (s == 0) ? bias[o] : 0.f;
    const int h = o >> 5, dj = o & 31;
    const int f = s * DH + dj;
    if (z < 2) {
        __hip_bfloat16* dst = (z == 0) ? qhB : khB;
        #pragma unroll
        for (int r = 0; r < 8; ++r)
            dst[((size_t)h * NATOM + (n0 + r)) * FDIM + f] = __float2bfloat16((acc[r] + bb) * scale);
    } else {
        __hip_bfloat16* dst = vhT + ((size_t)h * FDIM + f) * NATOM + n0;
        #pragma unroll
        for (int r = 0; r < 8; ++r) dst[r] = __float2bfloat16(acc[r] + bb);
    }
}

// ---------------- K2: MFMA scores: scoresA[h][n][m] = dot(qhB[h,n,:], khB[h,m,:]) ----------------
__global__ void __launch_bounds__(256) gemm_scores_mfma(const ushort* __restrict__ qhB,
                                                        const ushort* __restrict__ khB,
                                                        float* __restrict__ scoresA) {
    const int h = blockIdx.z;
    const int m0 = blockIdx.x * 64;
    const int n0 = blockIdx.y * 64;
    const int tid = threadIdx.x;
    const int lane = tid & 63, w = tid >> 6;
    const int wr = w >> 1, wc = w & 1;
    const int r = lane & 15, kg = lane >> 4;
    const ushort* A = qhB + (size_t)h * NATOM * FDIM;
    const ushort* B = khB + (size_t)h * NATOM * FDIM;
    const int ar = n0 + 32 * wr + r;
    const int br = m0 + 32 * wc + r;
    f32x4 acc00 = {}, acc01 = {}, acc10 = {}, acc11 = {};
    #pragma unroll
    for (int ks = 0; ks < FDIM / 32; ++ks) {
        const int k0 = ks * 32 + kg * 8;
        bf16x8 a0 = *(const bf16x8*)(A + (size_t)ar * FDIM + k0);
        bf16x8 a1 = *(const bf16x8*)(A + (size_t)(ar + 16) * FDIM + k0);
        bf16x8 b0 = *(const bf16x8*)(B + (size_t)br * FDIM + k0);
        bf16x8 b1 = *(const bf16x8*)(B + (size_t)(br + 16) * FDIM + k0);
        acc00 = __builtin_amdgcn_mfma_f32_16x16x32_bf16(a0, b0, acc00, 0, 0, 0);
        acc01 = __builtin_amdgcn_mfma_f32_16x16x32_bf16(a0, b1, acc01, 0, 0, 0);
        acc10 = __builtin_amdgcn_mfma_f32_16x16x32_bf16(a1, b0, acc10, 0, 0, 0);
        acc11 = __builtin_amdgcn_mfma_f32_16x16x32_bf16(a1, b1, acc11, 0, 0, 0);
    }
    #define STORE_SC(ACC, I, J) { \
        int row = n0 + 32 * wr + (I) * 16 + kg * 4; \
        int col = m0 + 32 * wc + (J) * 16 + r; \
        float* dst = scoresA + ((size_t)h * NATOM + row) * NATOM + col; \
        dst[0] = ACC[0]; dst[NATOM] = ACC[1]; dst[2 * NATOM] = ACC[2]; dst[3 * NATOM] = ACC[3]; }
    STORE_SC(acc00, 0, 0) STORE_SC(acc01, 0, 1) STORE_SC(acc10, 1, 0) STORE_SC(acc11, 1, 1)
    #undef STORE_SC
}

// ---------------- K3: wave-parallel collapsed segmented softmax (fp32 scores -> bf16 attn) ----------------
// attnA[h,n,m] = es[m] * sum_g E2[h,g,m] / (sum_m' es[m']*E1[h,g,m'] + 1e-30)
#define SMW_RPW 4
__global__ void __launch_bounds__(256) softmax_agg3(const float* __restrict__ scoresA,
                                                    ushort* __restrict__ attnB,
                                                    const float* __restrict__ E1,
                                                    const float* __restrict__ E2) {
    const int h = blockIdx.y;
    const int n0 = blockIdx.x * (4 * SMW_RPW);
    __shared__ float E1s[NSEG][NATOM];   // 32 KB
    __shared__ float E2s[NSEG][NATOM];   // 32 KB
    const int tid = threadIdx.x;
    const float* e1g = E1 + (size_t)h * NSEG * NATOM;
    const float* e2g = E2 + (size_t)h * NSEG * NATOM;
    for (int i = tid * 4; i < NSEG * NATOM; i += 1024) {
        *(float4*)&((float*)E1s)[i] = *(const float4*)&e1g[i];
        *(float4*)&((float*)E2s)[i] = *(const float4*)&e2g[i];
    }
    __syncthreads();
    const int lane = tid & 63, wid = tid >> 6;
    const int m0 = lane * 8;
    for (int rr = 0; rr < SMW_RPW; ++rr) {
        const int row = n0 + wid * SMW_RPW + rr;
        const float* srow = scoresA + ((size_t)h * NATOM + row) * NATOM;
        float4 sa = *(const float4*)(srow + m0);
        float4 sb = *(const float4*)(srow + m0 + 4);
        float s[8] = {sa.x, sa.y, sa.z, sa.w, sb.x, sb.y, sb.z, sb.w};
        float mx = fmaxf(fmaxf(fmaxf(s[0], s[1]), fmaxf(s[2], s[3])),
                         fmaxf(fmaxf(s[4], s[5]), fmaxf(s[6], s[7])));
        #pragma unroll
        for (int off = 32; off; off >>= 1) mx = fmaxf(mx, __shfl_xor(mx, off, 64));
        float es[8];
        #pragma unroll
        for (int j = 0; j < 8; ++j) es[j] = __expf(s[j] - mx);
        float D[NSEG];
        #pragma unroll
        for (int g = 0; g < NSEG; ++g) {
            float4 p = *(const float4*)&E1s[g][m0];
            float4 p2 = *(const float4*)&E1s[g][m0 + 4];
            D[g] = es[0] * p.x + es[1] * p.y + es[2] * p.z + es[3] * p.w
                 + es[4] * p2.x + es[5] * p2.y + es[6] * p2.z + es[7] * p2.w;
        }
        #pragma unroll
        for (int g = 0; g < NSEG; ++g) {
            float vv = D[g];
            #pragma unroll
            for (int off = 32; off; off >>= 1) vv += __shfl_xor(vv, off, 64);
            D[g] = vv;
        }
        float w[8] = {};
        #pragma unroll
        for (int g = 0; g < NSEG; ++g) {
            float iv = 1.0f / (D[g] + 1e-30f);
            float4 p = *(const float4*)&E2s[g][m0];
            float4 p2 = *(const float4*)&E2s[g][m0 + 4];
            w[0] += iv * p.x;  w[1] += iv * p.y;  w[2] += iv * p.z;  w[3] += iv * p.w;
            w[4] += iv * p2.x; w[5] += iv * p2.y; w[6] += iv * p2.z; w[7] += iv * p2.w;
        }
        ushort* arow = attnB + ((size_t)h * NATOM + row) * NATOM;
        short8 ov;
        #pragma unroll
        for (int j = 0; j < 8; ++j) {
            __hip_bfloat16 bv = __float2bfloat16(es[j] * w[j]);
            ov[j] = *(short*)&bv;
        }
        *(short8*)(arow + m0) = ov;
    }
}

// ---------------- K4: MFMA out: attnOut[n][s][h*32+dj] = sum_m attnB[h,n,m]*vhT[h,f,m] ----------------
__global__ void __launch_bounds__(256) gemm_out_mfma(const ushort* __restrict__ attnB,
                                                     const ushort* __restrict__ vhT,
                                                     float* __restrict__ attnOut) {
    const int h = blockIdx.z;
    const int f0 = blockIdx.x * 64;
    const int n0 = blockIdx.y * 64;
    const int tid = threadIdx.x;
    const int lane = tid & 63, w = tid >> 6;
    const int wr = w >> 1, wc = w & 1;
    const int r = lane & 15, kg = lane >> 4;
    const ushort* A = attnB + (size_t)h * NATOM * NATOM;
    const ushort* B = vhT + (size_t)h * FDIM * NATOM;
    const int ar = n0 + 32 * wr + r;
    const int br = f0 + 32 * wc + r;
    const bool b0ok = (f0 + 32 * wc) < FDIM;
    const bool b1ok = (f0 + 32 * wc + 16) < FDIM;
    f32x4 acc00 = {}, acc01 = {}, acc10 = {}, acc11 = {};
    const bf16x8 bz = {};
    #pragma unroll 4
    for (int ks = 0; ks < NATOM / 32; ++ks) {
        const int k0 = ks * 32 + kg * 8;
        bf16x8 a0 = *(const bf16x8*)(A + (size_t)ar * NATOM + k0);
        bf16x8 a1 = *(const bf16x8*)(A + (size_t)(ar + 16) * NATOM + k0);
        bf16x8 b0 = b0ok ? *(const bf16x8*)(B + (size_t)br * NATOM + k0) : bz;
        bf16x8 b1 = b1ok ? *(const bf16x8*)(B + (size_t)(br + 16) * NATOM + k0) : bz;
        acc00 = __builtin_amdgcn_mfma_f32_16x16x32_bf16(a0, b0, acc00, 0, 0, 0);
        acc01 = __builtin_amdgcn_mfma_f32_16x16x32_bf16(a0, b1, acc01, 0, 0, 0);
        acc10 = __builtin_amdgcn_mfma_f32_16x16x32_bf16(a1, b0, acc10, 0, 0, 0);
        acc11 = __builtin_amdgcn_mfma_f32_16x16x32_bf16(a1, b1, acc11, 0, 0, 0);
    }
    #define STORE_OUT(ACC, I, J) { \
        int row = n0 + 32 * wr + (I) * 16 + kg * 4; \
        int f = f0 + 32 * wc + (J) * 16 + r; \
        if (f < FDIM) { \
            int s = f >> 5, dj = f & 31; \
            float* dst = attnOut + ((size_t)row * SDIM + s) * CHN + h * DH + dj; \
            dst[0] = ACC[0]; dst[SDIM * CHN] = ACC[1]; dst[2 * SDIM * CHN] = ACC[2]; dst[3 * SDIM * CHN] = ACC[3]; } }
    STORE_OUT(acc00, 0, 0) STORE_OUT(acc01, 0, 1) STORE_OUT(acc10, 1, 0) STORE_OUT(acc11, 1, 1)
    #undef STORE_OUT
}

// ---------------- K5: fused equivariant layernorm + final so3_linear ----------------
// block = 2 atoms; stage 2x(9*256) in LDS, stats, normalize in place, then 256->128 GEMM
__global__ void __launch_bounds__(256) eqln_so3out(const float* __restrict__ xin,
                                                   const float* __restrict__ gamma,
                                                   const float* __restrict__ beta,
                                                   const float* __restrict__ Wo,
                                                   const float* __restrict__ bo,
                                                   float* __restrict__ out) {
    const int n0 = blockIdx.x * 2;
    __shared__ float ys[2][SDIM * CHN];      // 18 KB
    __shared__ float pstat[2][2][4];
    __shared__ float fac[2][4];
    const int tid = threadIdx.x;
    const float* src = xin + (size_t)n0 * SDIM * CHN;
    for (int i = tid; i < 2 * SDIM * CHN / 4; i += 256)
        ((float4*)ys)[i] = ((const float4*)src)[i];
    __syncthreads();
    // stats: wave (row, half) partitions
    const int lane = tid & 63, w = tid >> 6;
    const int row = w & 1, part = w >> 1;
    {
        float s0 = 0.f, q0 = 0.f, q1 = 0.f, q2 = 0.f;
        for (int i = lane + part * 64; i < SDIM * CHN; i += 128) {
            float x = ys[row][i];
            int s = i >> 8;
            if (s == 0) { s0 += x; q0 += x * x; }
            else if (s < 4) q1 += x * x;
            else q2 += x * x;
        }
        #pragma unroll
        for (int off = 32; off; off >>= 1) {
            s0 += __shfl_xor(s0, off, 64);
            q0 += __shfl_xor(q0, off, 64);
            q1 += __shfl_xor(q1, off, 64);
            q2 += __shfl_xor(q2, off, 64);
        }
        if (lane == 0) {
            pstat[row][part][0] = s0; pstat[row][part][1] = q0;
            pstat[row][part][2] = q1; pstat[row][part][3] = q2;
        }
    }
    __syncthreads();
    if (tid < 2) {
        float s0 = pstat[tid][0][0] + pstat[tid][1][0];
        float q0 = pstat[tid][0][1] + pstat[tid][1][1];
        float q1 = pstat[tid][0][2] + pstat[tid][1][2];
        float q2 = pstat[tid][0][3] + pstat[tid][1][3];
        float mu = s0 * (1.0f / CHN);
        float var = q0 * (1.0f / CHN) - mu * mu;
        fac[tid][0] = mu;
        fac[tid][1] = 1.0f / sqrtf(var + EPS);
        fac[tid][2] = 1.0f / sqrtf(q1 * (1.0f / (3 * CHN)) + EPS);
        fac[tid][3] = 1.0f / sqrtf(q2 * (1.0f / (5 * CHN)) + EPS);
    }
    __syncthreads();
    // normalize in place
    for (int i = tid; i < 2 * SDIM * CHN / 4; i += 256) {
        int r = (i * 4) / (SDIM * CHN);
        int f = i * 4 - r * (SDIM * CHN);
        int s = f >> 8, c = f & 255;
        float4 x = ((float4*)ys)[i];
        float* xp = (float*)&x;
        if (s == 0) {
            float mu = fac[r][0], iv = fac[r][1];
            #pragma unroll
            for (int j = 0; j < 4; ++j)
                xp[j] = (xp[j] - mu) * iv * gamma[c + j] + beta[c + j];
        } else {
            float iv = (s < 4) ? fac[r][2] : fac[r][3];
            const float* g = gamma + ((s < 4) ? CHN : 2 * CHN);
            #pragma unroll
            for (int j = 0; j < 4; ++j) xp[j] = xp[j] * iv * g[c + j];
        }
        ((float4*)ys)[i] = x;
    }
    __syncthreads();
    // GEMM: out[n0+r][s][o] = sum_c ys[r][s*256+c] * Wo[l(s)][c][o] (+bo at s==0)
    const int o = tid & 127, r2 = tid >> 7;
    float acc[SDIM] = {};
    #pragma unroll 2
    for (int c = 0; c < CHN; ++c) {
        float w0 = Wo[(size_t)c * CIN + o];
        float w1 = Wo[(size_t)(CHN + c) * CIN + o];
        float w2 = Wo[(size_t)(2 * CHN + c) * CIN + o];
        const float* yr = &ys[r2][c];
        acc[0] += yr[0] * w0;
        #pragma unroll
        for (int s = 1; s < 4; ++s) acc[s] += yr[s * 256] * w1;
        #pragma unroll
        for (int s = 4; s < SDIM; ++s) acc[s] += yr[s * 256] * w2;
    }
    float* dst = out + (size_t)(n0 + r2) * SDIM * CIN + o;
    float bb = bo[o];
    #pragma unroll
    for (int s = 0; s < SDIM; ++s)
        dst[s * CIN] = acc[s] + ((s == 0) ? bb : 0.f);
}

extern "C" void kernel_launch(void* const* d_in, const int* in_sizes, int n_in,
                              void* d_out, int out_size, void* d_ws, size_t ws_size,
                              hipStream_t stream) {
    const float* q = (const float*)d_in[0];
    const float* k = (const float*)d_in[1];
    const float* v = (const float*)d_in[2];
    const float* envelope = (const float*)d_in[3];
    const float* attn_bias = (const float*)d_in[4];
    const int* atom_index = (const int*)d_in[5];
    const int* batch_index = (const int*)d_in[6];
    const int* edge_map = (const int*)d_in[7];
    const float* Wq = (const float*)d_in[8];
    const float* bq = (const float*)d_in[9];
    const float* Wk = (const float*)d_in[10];
    const float* bk = (const float*)d_in[11];
    const float* Wv = (const float*)d_in[12];
    const float* bv = (const float*)d_in[13];
    const float* gamma = (const float*)d_in[14];
    const float* beta = (const float*)d_in[15];
    const float* Wo = (const float*)d_in[16];
    const float* bo = (const float*)d_in[17];
    float* out = (float*)d_out;

    const size_t SZ_HNF = (size_t)NH * NATOM * FDIM;      // 1,179,648 elems
    const size_t SZ_HNN = (size_t)NH * NATOM * NATOM;     // 2,097,152 elems
    const size_t SZ_TAB = (size_t)NH * NSEG * NATOM;      // 65,536 elems

    char* wsb = (char*)d_ws;
    __hip_bfloat16* qhB = (__hip_bfloat16*)wsb;                         // 2 * SZ_HNF bytes
    __hip_bfloat16* khB = qhB + SZ_HNF;
    __hip_bfloat16* vhT = khB + SZ_HNF;                                 // [h][f][n]
    float* scoresA = (float*)(vhT + SZ_HNF);                            // 4 * SZ_HNN bytes
    __hip_bfloat16* attnB = (__hip_bfloat16*)(scoresA + SZ_HNN);        // 2 * SZ_HNN bytes
    float* E1 = (float*)(attnB + SZ_HNN);
    float* E2 = E1 + SZ_TAB;
    float* attnOut = scoresA;                 // reuse: scoresA dead after softmax

    size_t needed = 2 * 3 * SZ_HNF + 4 * SZ_HNN + 2 * SZ_HNN + 4 * 2 * SZ_TAB + 256;
    if (ws_size < needed) return;

    prep_all<<<NSEG * NH + 3 * 64 * SDIM, 256, 0, stream>>>(
        batch_index, atom_index, edge_map, envelope, attn_bias, E1, E2,
        q, k, v, Wq, Wk, Wv, bq, bk, bv, qhB, khB, vhT);
    gemm_scores_mfma<<<dim3(NATOM / 64, NATOM / 64, NH), 256, 0, stream>>>(
        (const ushort*)qhB, (const ushort*)khB, scoresA);
    softmax_agg3<<<dim3(NATOM / (4 * SMW_RPW), NH), 256, 0, stream>>>(
        scoresA, (ushort*)attnB, E1, E2);
    gemm_out_mfma<<<dim3((FDIM + 63) / 64, NATOM / 64, NH), 256, 0, stream>>>(
        (const ushort*)attnB, (const ushort*)vhT, attnOut);
    eqln_so3out<<<NATOM / 2, 256, 0, stream>>>(attnOut, gamma, beta, Wo, bo, out);
}

// Round 6
// 89.202 us; speedup vs baseline: 1.3570x; 1.3570x over previous
//
#include <hip/hip_runtime.h>
#include <hip/hip_bf16.h>
#include <math.h>

#define NH 8
#define SDIM 9
#define NSEG 16
#define NATOM 512
#define NEDGE 8192
#define CIN 128
#define CHN 256
#define DH 32
#define FDIM 288            // SDIM*DH
#define EPS 1e-7f
#define SCALE 0.10206207261596577f   // sqrt(32/3)/32

typedef __attribute__((ext_vector_type(8))) short bf16x8;
typedef __attribute__((ext_vector_type(8))) short short8;
typedef __attribute__((ext_vector_type(4))) float f32x4;

// ---------------- block reduce helpers (blockDim.x == 256) ----------------
__device__ inline float blockReduceMax(float v, float* red) {
    #pragma unroll
    for (int off = 32; off; off >>= 1) v = fmaxf(v, __shfl_xor(v, off, 64));
    int lane = threadIdx.x & 63, wid = threadIdx.x >> 6;
    if (lane == 0) red[wid] = v;
    __syncthreads();
    v = fmaxf(fmaxf(red[0], red[1]), fmaxf(red[2], red[3]));
    __syncthreads();
    return v;
}
__device__ inline float blockReduceSum(float v, float* red) {
    #pragma unroll
    for (int off = 32; off; off >>= 1) v += __shfl_xor(v, off, 64);
    int lane = threadIdx.x & 63, wid = threadIdx.x >> 6;
    if (lane == 0) red[wid] = v;
    __syncthreads();
    v = red[0] + red[1] + red[2] + red[3];
    __syncthreads();
    return v;
}

__device__ inline int lower_bound_batch(const int* __restrict__ b, int val) {
    int lo = 0, hi = NEDGE;
    while (lo < hi) {
        int mid = (lo + hi) >> 1;
        if (b[mid] < val) lo = mid + 1; else hi = mid;
    }
    return lo;
}

// ---------------- K1: fused prep: seg tables + q/k/v projections + WoT transpose ----------------
// blocks [0,128): E1/E2 seg tables; [128,1856): qkv projections; [1856,1904): WoT bf16 transpose
__global__ void __launch_bounds__(256) prep_all(const int* __restrict__ batch,
                                                const int* __restrict__ am, const int* __restrict__ emap,
                                                const float* __restrict__ envelope,
                                                const float* __restrict__ attn_bias,
                                                float* __restrict__ E1, float* __restrict__ E2,
                                                const float* __restrict__ q, const float* __restrict__ k,
                                                const float* __restrict__ v,
                                                const float* __restrict__ Wq, const float* __restrict__ Wk,
                                                const float* __restrict__ Wv,
                                                const float* __restrict__ bq, const float* __restrict__ bk,
                                                const float* __restrict__ bv,
                                                __hip_bfloat16* __restrict__ qhB,
                                                __hip_bfloat16* __restrict__ khB,
                                                __hip_bfloat16* __restrict__ vhT,
                                                const float* __restrict__ Wo,
                                                ushort* __restrict__ WoT) {
    const int bid = blockIdx.x;
    const int tid = threadIdx.x;
    if (bid < NSEG * NH) {
        // ---- segment table part ----
        const int seg = bid & (NSEG - 1), h = bid >> 4;
        __shared__ float e1[NATOM];
        __shared__ float e2[NATOM];
        __shared__ float red[4];
        e1[tid] = 0.f; e1[tid + 256] = 0.f;
        e2[tid] = 0.f; e2[tid + 256] = 0.f;
        const float* bh = attn_bias + (size_t)h * NEDGE;
        float mv = -1e30f;
        for (int e = tid; e < NEDGE; e += 256) mv = fmaxf(mv, bh[e]);
        const float mb = blockReduceMax(mv, red);   // barrier inside covers e1/e2 init
        const int st = lower_bound_batch(batch, seg);
        const int en = lower_bound_batch(batch, seg + 1);
        for (int e = st + tid; e < en; e += 256) {
            int m = am[e], em = emap[e];
            float ev = envelope[em];
            float eb = __expf(bh[em] - mb);
            atomicAdd(&e1[m], ev * eb);
            atomicAdd(&e2[m], ev * ev * eb);
        }
        __syncthreads();
        size_t base = ((size_t)h * NSEG + seg) * NATOM;
        E1[base + tid] = e1[tid]; E1[base + tid + 256] = e1[tid + 256];
        E2[base + tid] = e2[tid]; E2[base + tid + 256] = e2[tid + 256];
        return;
    }
    if (bid < NSEG * NH + 3 * 64 * SDIM) {
        // ---- projection part ----
        const int idx = bid - NSEG * NH;
        const int z = idx / (64 * SDIM);
        const int rem = idx - z * 64 * SDIM;
        const int s = rem >> 6;
        const int n0 = (rem & 63) * 8;
        const float* x = (z == 0) ? q : (z == 1) ? k : v;
        const float* W = (z == 0) ? Wq : (z == 1) ? Wk : Wv;
        const float* bias = (z == 0) ? bq : (z == 1) ? bk : bv;
        const float scale = (z == 0) ? SCALE : 1.0f;
        const int l = (s == 0) ? 0 : ((s < 4) ? 1 : 2);
        __shared__ float xs[8][CIN];
        for (int i2 = tid; i2 < 8 * CIN; i2 += 256) {
            int r = i2 >> 7, i = i2 & 127;
            xs[r][i] = x[((size_t)(n0 + r) * SDIM + s) * CIN + i];
        }
        __syncthreads();
        const int o = tid;
        const float* Wl = W + (size_t)l * CIN * CHN + o;
        float acc[8] = {0, 0, 0, 0, 0, 0, 0, 0};
        #pragma unroll 4
        for (int i = 0; i < CIN; ++i) {
            float w = Wl[(size_t)i * CHN];
            #pragma unroll
            for (int r = 0; r < 8; ++r) acc[r] += xs[r][i] * w;
        }
        float bb = (s == 0) ? bias[o] : 0.f;
        const int h = o >> 5, dj = o & 31;
        const int f = s * DH + dj;
        if (z < 2) {
            __hip_bfloat16* dst = (z == 0) ? qhB : khB;
            #pragma unroll
            for (int r = 0; r < 8; ++r)
                dst[((size_t)h * NATOM + (n0 + r)) * FDIM + f] = __float2bfloat16((acc[r] + bb) * scale);
        } else {
            __hip_bfloat16* dst = vhT + ((size_t)h * FDIM + f) * NATOM + n0;
            #pragma unroll
            for (int r = 0; r < 8; ++r) dst[r] = __float2bfloat16(acc[r] + bb);
        }
        return;
    }
    // ---- WoT transpose part: WoT[l][o][c] = bf16(Wo[l][c][o]) ----
    // blocks: (l, cb, ob): c0 = cb*64, o0 = ob*32; grid 3*4*4 = 48
    {
        const int t = bid - (NSEG * NH + 3 * 64 * SDIM);
        const int l = t / 16;
        const int cb = (t & 15) >> 2, ob = t & 3;
        const int c0 = cb * 64, o0 = ob * 32;
        __shared__ float tile[64][33];
        const float* src = Wo + (size_t)l * CHN * CIN;
        #pragma unroll
        for (int p = 0; p < 8; ++p) {
            int row = p * 8 + (tid >> 5);       // c offset
            int col = tid & 31;                 // o offset
            tile[row][col] = src[(size_t)(c0 + row) * CIN + o0 + col];
        }
        __syncthreads();
        ushort* dst = WoT + (size_t)l * CIN * CHN;
        #pragma unroll
        for (int p = 0; p < 8; ++p) {
            int o = p * 4 + (tid >> 6);         // o offset (0..31)
            int c = tid & 63;                   // c offset (0..63)
            __hip_bfloat16 bvv = __float2bfloat16(tile[c][o]);
            dst[(size_t)(o0 + o) * CHN + c0 + c] = *(ushort*)&bvv;
        }
    }
}

// ---------------- K2: MFMA scores: scoresA[h][n][m] = dot(qhB[h,n,:], khB[h,m,:]) ----------------
__global__ void __launch_bounds__(256) gemm_scores_mfma(const ushort* __restrict__ qhB,
                                                        const ushort* __restrict__ khB,
                                                        float* __restrict__ scoresA) {
    const int h = blockIdx.z;
    const int m0 = blockIdx.x * 64;
    const int n0 = blockIdx.y * 64;
    const int tid = threadIdx.x;
    const int lane = tid & 63, w = tid >> 6;
    const int wr = w >> 1, wc = w & 1;
    const int r = lane & 15, kg = lane >> 4;
    const ushort* A = qhB + (size_t)h * NATOM * FDIM;
    const ushort* B = khB + (size_t)h * NATOM * FDIM;
    const int ar = n0 + 32 * wr + r;
    const int br = m0 + 32 * wc + r;
    f32x4 acc00 = {}, acc01 = {}, acc10 = {}, acc11 = {};
    #pragma unroll
    for (int ks = 0; ks < FDIM / 32; ++ks) {
        const int k0 = ks * 32 + kg * 8;
        bf16x8 a0 = *(const bf16x8*)(A + (size_t)ar * FDIM + k0);
        bf16x8 a1 = *(const bf16x8*)(A + (size_t)(ar + 16) * FDIM + k0);
        bf16x8 b0 = *(const bf16x8*)(B + (size_t)br * FDIM + k0);
        bf16x8 b1 = *(const bf16x8*)(B + (size_t)(br + 16) * FDIM + k0);
        acc00 = __builtin_amdgcn_mfma_f32_16x16x32_bf16(a0, b0, acc00, 0, 0, 0);
        acc01 = __builtin_amdgcn_mfma_f32_16x16x32_bf16(a0, b1, acc01, 0, 0, 0);
        acc10 = __builtin_amdgcn_mfma_f32_16x16x32_bf16(a1, b0, acc10, 0, 0, 0);
        acc11 = __builtin_amdgcn_mfma_f32_16x16x32_bf16(a1, b1, acc11, 0, 0, 0);
    }
    #define STORE_SC(ACC, I, J) { \
        int row = n0 + 32 * wr + (I) * 16 + kg * 4; \
        int col = m0 + 32 * wc + (J) * 16 + r; \
        float* dst = scoresA + ((size_t)h * NATOM + row) * NATOM + col; \
        dst[0] = ACC[0]; dst[NATOM] = ACC[1]; dst[2 * NATOM] = ACC[2]; dst[3 * NATOM] = ACC[3]; }
    STORE_SC(acc00, 0, 0) STORE_SC(acc01, 0, 1) STORE_SC(acc10, 1, 0) STORE_SC(acc11, 1, 1)
    #undef STORE_SC
}

// ---------------- K3: wave-parallel collapsed segmented softmax (fp32 scores -> bf16 attn) ----------------
#define SMW_RPW 4
__global__ void __launch_bounds__(256) softmax_agg3(const float* __restrict__ scoresA,
                                                    ushort* __restrict__ attnB,
                                                    const float* __restrict__ E1,
                                                    const float* __restrict__ E2) {
    const int h = blockIdx.y;
    const int n0 = blockIdx.x * (4 * SMW_RPW);
    __shared__ float E1s[NSEG][NATOM];   // 32 KB
    __shared__ float E2s[NSEG][NATOM];   // 32 KB
    const int tid = threadIdx.x;
    const float* e1g = E1 + (size_t)h * NSEG * NATOM;
    const float* e2g = E2 + (size_t)h * NSEG * NATOM;
    for (int i = tid * 4; i < NSEG * NATOM; i += 1024) {
        *(float4*)&((float*)E1s)[i] = *(const float4*)&e1g[i];
        *(float4*)&((float*)E2s)[i] = *(const float4*)&e2g[i];
    }
    __syncthreads();
    const int lane = tid & 63, wid = tid >> 6;
    const int m0 = lane * 8;
    for (int rr = 0; rr < SMW_RPW; ++rr) {
        const int row = n0 + wid * SMW_RPW + rr;
        const float* srow = scoresA + ((size_t)h * NATOM + row) * NATOM;
        float4 sa = *(const float4*)(srow + m0);
        float4 sb = *(const float4*)(srow + m0 + 4);
        float s[8] = {sa.x, sa.y, sa.z, sa.w, sb.x, sb.y, sb.z, sb.w};
        float mx = fmaxf(fmaxf(fmaxf(s[0], s[1]), fmaxf(s[2], s[3])),
                         fmaxf(fmaxf(s[4], s[5]), fmaxf(s[6], s[7])));
        #pragma unroll
        for (int off = 32; off; off >>= 1) mx = fmaxf(mx, __shfl_xor(mx, off, 64));
        float es[8];
        #pragma unroll
        for (int j = 0; j < 8; ++j) es[j] = __expf(s[j] - mx);
        float D[NSEG];
        #pragma unroll
        for (int g = 0; g < NSEG; ++g) {
            float4 p = *(const float4*)&E1s[g][m0];
            float4 p2 = *(const float4*)&E1s[g][m0 + 4];
            D[g] = es[0] * p.x + es[1] * p.y + es[2] * p.z + es[3] * p.w
                 + es[4] * p2.x + es[5] * p2.y + es[6] * p2.z + es[7] * p2.w;
        }
        #pragma unroll
        for (int g = 0; g < NSEG; ++g) {
            float vv = D[g];
            #pragma unroll
            for (int off = 32; off; off >>= 1) vv += __shfl_xor(vv, off, 64);
            D[g] = vv;
        }
        float w[8] = {};
        #pragma unroll
        for (int g = 0; g < NSEG; ++g) {
            float iv = 1.0f / (D[g] + 1e-30f);
            float4 p = *(const float4*)&E2s[g][m0];
            float4 p2 = *(const float4*)&E2s[g][m0 + 4];
            w[0] += iv * p.x;  w[1] += iv * p.y;  w[2] += iv * p.z;  w[3] += iv * p.w;
            w[4] += iv * p2.x; w[5] += iv * p2.y; w[6] += iv * p2.z; w[7] += iv * p2.w;
        }
        ushort* arow = attnB + ((size_t)h * NATOM + row) * NATOM;
        short8 ov;
        #pragma unroll
        for (int j = 0; j < 8; ++j) {
            __hip_bfloat16 bv = __float2bfloat16(es[j] * w[j]);
            ov[j] = *(short*)&bv;
        }
        *(short8*)(arow + m0) = ov;
    }
}

// ---------------- K4: MFMA out: attnOut[n][s][h*32+dj] = sum_m attnB[h,n,m]*vhT[h,f,m] ----------------
__global__ void __launch_bounds__(256) gemm_out_mfma(const ushort* __restrict__ attnB,
                                                     const ushort* __restrict__ vhT,
                                                     float* __restrict__ attnOut) {
    const int h = blockIdx.z;
    const int f0 = blockIdx.x * 64;
    const int n0 = blockIdx.y * 64;
    const int tid = threadIdx.x;
    const int lane = tid & 63, w = tid >> 6;
    const int wr = w >> 1, wc = w & 1;
    const int r = lane & 15, kg = lane >> 4;
    const ushort* A = attnB + (size_t)h * NATOM * NATOM;
    const ushort* B = vhT + (size_t)h * FDIM * NATOM;
    const int ar = n0 + 32 * wr + r;
    const int br = f0 + 32 * wc + r;
    const bool b0ok = (f0 + 32 * wc) < FDIM;
    const bool b1ok = (f0 + 32 * wc + 16) < FDIM;
    f32x4 acc00 = {}, acc01 = {}, acc10 = {}, acc11 = {};
    const bf16x8 bz = {};
    #pragma unroll 4
    for (int ks = 0; ks < NATOM / 32; ++ks) {
        const int k0 = ks * 32 + kg * 8;
        bf16x8 a0 = *(const bf16x8*)(A + (size_t)ar * NATOM + k0);
        bf16x8 a1 = *(const bf16x8*)(A + (size_t)(ar + 16) * NATOM + k0);
        bf16x8 b0 = b0ok ? *(const bf16x8*)(B + (size_t)br * NATOM + k0) : bz;
        bf16x8 b1 = b1ok ? *(const bf16x8*)(B + (size_t)(br + 16) * NATOM + k0) : bz;
        acc00 = __builtin_amdgcn_mfma_f32_16x16x32_bf16(a0, b0, acc00, 0, 0, 0);
        acc01 = __builtin_amdgcn_mfma_f32_16x16x32_bf16(a0, b1, acc01, 0, 0, 0);
        acc10 = __builtin_amdgcn_mfma_f32_16x16x32_bf16(a1, b0, acc10, 0, 0, 0);
        acc11 = __builtin_amdgcn_mfma_f32_16x16x32_bf16(a1, b1, acc11, 0, 0, 0);
    }
    #define STORE_OUT(ACC, I, J) { \
        int row = n0 + 32 * wr + (I) * 16 + kg * 4; \
        int f = f0 + 32 * wc + (J) * 16 + r; \
        if (f < FDIM) { \
            int s = f >> 5, dj = f & 31; \
            float* dst = attnOut + ((size_t)row * SDIM + s) * CHN + h * DH + dj; \
            dst[0] = ACC[0]; dst[SDIM * CHN] = ACC[1]; dst[2 * SDIM * CHN] = ACC[2]; dst[3 * SDIM * CHN] = ACC[3]; } }
    STORE_OUT(acc00, 0, 0) STORE_OUT(acc01, 0, 1) STORE_OUT(acc10, 1, 0) STORE_OUT(acc11, 1, 1)
    #undef STORE_OUT
}

// ---------------- K5: equivariant layernorm -> bf16 normalized (H-free (N,S,CHN) layout) ----------------
__global__ void __launch_bounds__(256) eqln_bf16(const float* __restrict__ xin,
                                                 const float* __restrict__ gamma,
                                                 const float* __restrict__ beta,
                                                 ushort* __restrict__ outn) {
    const int n = blockIdx.x;
    const int c = threadIdx.x;
    __shared__ float red[4];
    float xv[SDIM];
    #pragma unroll
    for (int s = 0; s < SDIM; ++s) xv[s] = xin[((size_t)n * SDIM + s) * CHN + c];
    float mu = blockReduceSum(xv[0], red) * (1.0f / CHN);
    float dv = xv[0] - mu;
    float var = blockReduceSum(dv * dv, red) * (1.0f / CHN);
    float y0 = dv / sqrtf(var + EPS) * gamma[c] + beta[c];
    {
        __hip_bfloat16 bvv = __float2bfloat16(y0);
        outn[(size_t)n * SDIM * CHN + c] = *(ushort*)&bvv;
    }
    float n2 = (xv[1] * xv[1] + xv[2] * xv[2] + xv[3] * xv[3]) * (1.0f / 3.0f);
    float ms = blockReduceSum(n2, red) * (1.0f / CHN);
    float inv1 = 1.0f / sqrtf(ms + EPS);
    #pragma unroll
    for (int s = 1; s < 4; ++s) {
        __hip_bfloat16 bvv = __float2bfloat16(xv[s] * inv1 * gamma[CHN + c]);
        outn[((size_t)n * SDIM + s) * CHN + c] = *(ushort*)&bvv;
    }
    float n22 = (xv[4] * xv[4] + xv[5] * xv[5] + xv[6] * xv[6] + xv[7] * xv[7] + xv[8] * xv[8]) * (1.0f / 5.0f);
    float ms2 = blockReduceSum(n22, red) * (1.0f / CHN);
    float inv2 = 1.0f / sqrtf(ms2 + EPS);
    #pragma unroll
    for (int s = 4; s < SDIM; ++s) {
        __hip_bfloat16 bvv = __float2bfloat16(xv[s] * inv2 * gamma[2 * CHN + c]);
        outn[((size_t)n * SDIM + s) * CHN + c] = *(ushort*)&bvv;
    }
}

// ---------------- K6: MFMA final projection: out[n][s][o] = sum_c normedB[n,s,c]*WoT[l(s),o,c] ----------------
__global__ void __launch_bounds__(256) so3out_mfma(const ushort* __restrict__ normedB,
                                                   const ushort* __restrict__ WoT,
                                                   const float* __restrict__ bo,
                                                   float* __restrict__ out) {
    const int s = blockIdx.y;
    const int n0 = blockIdx.x * 64;
    const int l = (s == 0) ? 0 : ((s < 4) ? 1 : 2);
    const int tid = threadIdx.x;
    const int lane = tid & 63, w = tid >> 6;
    const int wr = w >> 1, wc = w & 1;
    const int r = lane & 15, kg = lane >> 4;
    const ushort* B = WoT + (size_t)l * CIN * CHN;
    const int ar = n0 + 32 * wr + r;
    const int bc = 64 * wc;
    f32x4 acc[2][4] = {};
    #pragma unroll
    for (int ks = 0; ks < CHN / 32; ++ks) {
        const int k0 = ks * 32 + kg * 8;
        bf16x8 a0 = *(const bf16x8*)(normedB + ((size_t)ar * SDIM + s) * CHN + k0);
        bf16x8 a1 = *(const bf16x8*)(normedB + ((size_t)(ar + 16) * SDIM + s) * CHN + k0);
        bf16x8 b[4];
        #pragma unroll
        for (int j = 0; j < 4; ++j)
            b[j] = *(const bf16x8*)(B + (size_t)(bc + 16 * j + r) * CHN + k0);
        #pragma unroll
        for (int j = 0; j < 4; ++j) {
            acc[0][j] = __builtin_amdgcn_mfma_f32_16x16x32_bf16(a0, b[j], acc[0][j], 0, 0, 0);
            acc[1][j] = __builtin_amdgcn_mfma_f32_16x16x32_bf16(a1, b[j], acc[1][j], 0, 0, 0);
        }
    }
    #pragma unroll
    for (int i = 0; i < 2; ++i) {
        #pragma unroll
        for (int j = 0; j < 4; ++j) {
            int n = n0 + 32 * wr + 16 * i + kg * 4;
            int o = bc + 16 * j + r;
            float badd = (s == 0) ? bo[o] : 0.f;
            float* dst = out + ((size_t)n * SDIM + s) * CIN + o;
            dst[0] = acc[i][j][0] + badd;
            dst[SDIM * CIN] = acc[i][j][1] + badd;
            dst[2 * SDIM * CIN] = acc[i][j][2] + badd;
            dst[3 * SDIM * CIN] = acc[i][j][3] + badd;
        }
    }
}

extern "C" void kernel_launch(void* const* d_in, const int* in_sizes, int n_in,
                              void* d_out, int out_size, void* d_ws, size_t ws_size,
                              hipStream_t stream) {
    const float* q = (const float*)d_in[0];
    const float* k = (const float*)d_in[1];
    const float* v = (const float*)d_in[2];
    const float* envelope = (const float*)d_in[3];
    const float* attn_bias = (const float*)d_in[4];
    const int* atom_index = (const int*)d_in[5];
    const int* batch_index = (const int*)d_in[6];
    const int* edge_map = (const int*)d_in[7];
    const float* Wq = (const float*)d_in[8];
    const float* bq = (const float*)d_in[9];
    const float* Wk = (const float*)d_in[10];
    const float* bk = (const float*)d_in[11];
    const float* Wv = (const float*)d_in[12];
    const float* bv = (const float*)d_in[13];
    const float* gamma = (const float*)d_in[14];
    const float* beta = (const float*)d_in[15];
    const float* Wo = (const float*)d_in[16];
    const float* bo = (const float*)d_in[17];
    float* out = (float*)d_out;

    const size_t SZ_HNF = (size_t)NH * NATOM * FDIM;      // 1,179,648 elems
    const size_t SZ_HNN = (size_t)NH * NATOM * NATOM;     // 2,097,152 elems
    const size_t SZ_TAB = (size_t)NH * NSEG * NATOM;      // 65,536 elems
    const size_t SZ_WOT = (size_t)3 * CIN * CHN;          // 98,304 elems

    char* wsb = (char*)d_ws;
    __hip_bfloat16* qhB = (__hip_bfloat16*)wsb;                         // 2 * SZ_HNF bytes
    __hip_bfloat16* khB = qhB + SZ_HNF;
    __hip_bfloat16* vhT = khB + SZ_HNF;                                 // [h][f][n]
    float* scoresA = (float*)(vhT + SZ_HNF);                            // 4 * SZ_HNN bytes
    __hip_bfloat16* attnB = (__hip_bfloat16*)(scoresA + SZ_HNN);        // 2 * SZ_HNN bytes
    float* E1 = (float*)(attnB + SZ_HNN);
    float* E2 = E1 + SZ_TAB;
    ushort* WoT = (ushort*)(E2 + SZ_TAB);                               // 2 * SZ_WOT bytes
    float* attnOut = scoresA;                 // reuse: scoresA dead after softmax
    ushort* normedB = (ushort*)qhB;           // reuse: qhB dead after gemm_scores

    size_t needed = 2 * 3 * SZ_HNF + 4 * SZ_HNN + 2 * SZ_HNN + 4 * 2 * SZ_TAB + 2 * SZ_WOT + 256;
    if (ws_size < needed) return;

    prep_all<<<NSEG * NH + 3 * 64 * SDIM + 48, 256, 0, stream>>>(
        batch_index, atom_index, edge_map, envelope, attn_bias, E1, E2,
        q, k, v, Wq, Wk, Wv, bq, bk, bv, qhB, khB, vhT, Wo, WoT);
    gemm_scores_mfma<<<dim3(NATOM / 64, NATOM / 64, NH), 256, 0, stream>>>(
        (const ushort*)qhB, (const ushort*)khB, scoresA);
    softmax_agg3<<<dim3(NATOM / (4 * SMW_RPW), NH), 256, 0, stream>>>(
        scoresA, (ushort*)attnB, E1, E2);
    gemm_out_mfma<<<dim3((FDIM + 63) / 64, NATOM / 64, NH), 256, 0, stream>>>(
        (const ushort*)attnB, (const ushort*)vhT, attnOut);
    eqln_bf16<<<NATOM, 256, 0, stream>>>(attnOut, gamma, beta, normedB);
    so3out_mfma<<<dim3(NATOM / 64, SDIM), 256, 0, stream>>>(normedB, WoT, bo, out);
}

// Round 7
// 78.131 us; speedup vs baseline: 1.5493x; 1.1417x over previous
//
#include <hip/hip_runtime.h>
#include <hip/hip_bf16.h>
#include <math.h>

#define NH 8
#define SDIM 9
#define NSEG 16
#define NATOM 512
#define NEDGE 8192
#define CIN 128
#define CHN 256
#define DH 32
#define FDIM 288            // SDIM*DH
#define EPS 1e-7f
#define SCALE 0.10206207261596577f   // sqrt(32/3)/32

typedef __attribute__((ext_vector_type(8))) short bf16x8;
typedef __attribute__((ext_vector_type(8))) short short8;
typedef __attribute__((ext_vector_type(4))) float f32x4;

// ---------------- helpers ----------------
__device__ inline float blockReduceMax(float v, float* red) {
    #pragma unroll
    for (int off = 32; off; off >>= 1) v = fmaxf(v, __shfl_xor(v, off, 64));
    int lane = threadIdx.x & 63, wid = threadIdx.x >> 6;
    if (lane == 0) red[wid] = v;
    __syncthreads();
    v = fmaxf(fmaxf(red[0], red[1]), fmaxf(red[2], red[3]));
    __syncthreads();
    return v;
}
__device__ inline float blockReduceSum(float v, float* red) {
    #pragma unroll
    for (int off = 32; off; off >>= 1) v += __shfl_xor(v, off, 64);
    int lane = threadIdx.x & 63, wid = threadIdx.x >> 6;
    if (lane == 0) red[wid] = v;
    __syncthreads();
    v = red[0] + red[1] + red[2] + red[3];
    __syncthreads();
    return v;
}
__device__ inline int lower_bound_batch(const int* __restrict__ b, int val) {
    int lo = 0, hi = NEDGE;
    while (lo < hi) {
        int mid = (lo + hi) >> 1;
        if (b[mid] < val) lo = mid + 1; else hi = mid;
    }
    return lo;
}
__device__ inline ushort f2bu(float x) {
    __hip_bfloat16 b = __float2bfloat16(x);
    return *(ushort*)&b;
}

// ---------------- K1: fused stage1: seg tables + WoT transpose + MFMA qkv projections ----------------
// blocks [0,128): E1/E2 seg tables; [128,176): WoT; [176,608): qkv proj (MFMA)
__global__ void __launch_bounds__(256) stage1(const int* __restrict__ batch,
                                              const int* __restrict__ am, const int* __restrict__ emap,
                                              const float* __restrict__ envelope,
                                              const float* __restrict__ attn_bias,
                                              float* __restrict__ E1, float* __restrict__ E2,
                                              const float* __restrict__ q, const float* __restrict__ k,
                                              const float* __restrict__ v,
                                              const float* __restrict__ Wq, const float* __restrict__ Wk,
                                              const float* __restrict__ Wv,
                                              const float* __restrict__ bq, const float* __restrict__ bk,
                                              const float* __restrict__ bv,
                                              ushort* __restrict__ qhB,
                                              ushort* __restrict__ khB,
                                              ushort* __restrict__ vhT,
                                              const float* __restrict__ Wo,
                                              ushort* __restrict__ WoT) {
    const int bid = blockIdx.x;
    const int tid = threadIdx.x;
    if (bid < NSEG * NH) {
        // ---- segment table part ----
        const int seg = bid & (NSEG - 1), h = bid >> 4;
        __shared__ float e1[NATOM];
        __shared__ float e2[NATOM];
        __shared__ float red[4];
        e1[tid] = 0.f; e1[tid + 256] = 0.f;
        e2[tid] = 0.f; e2[tid + 256] = 0.f;
        const float* bh = attn_bias + (size_t)h * NEDGE;
        float mv = -1e30f;
        for (int e = tid; e < NEDGE; e += 256) mv = fmaxf(mv, bh[e]);
        const float mb = blockReduceMax(mv, red);   // barrier inside covers e1/e2 init
        const int st = lower_bound_batch(batch, seg);
        const int en = lower_bound_batch(batch, seg + 1);
        for (int e = st + tid; e < en; e += 256) {
            int m = am[e], em = emap[e];
            float ev = envelope[em];
            float eb = __expf(bh[em] - mb);
            atomicAdd(&e1[m], ev * eb);
            atomicAdd(&e2[m], ev * ev * eb);
        }
        __syncthreads();
        size_t base = ((size_t)h * NSEG + seg) * NATOM;
        E1[base + tid] = e1[tid]; E1[base + tid + 256] = e1[tid + 256];
        E2[base + tid] = e2[tid]; E2[base + tid + 256] = e2[tid + 256];
        return;
    }
    if (bid < NSEG * NH + 48) {
        // ---- WoT transpose: WoT[l][o][c] = bf16(Wo[l][c][o]) ----
        const int t = bid - NSEG * NH;
        const int l = t / 16;
        const int cb = (t & 15) >> 2, ob = t & 3;
        const int c0 = cb * 64, o0 = ob * 32;
        __shared__ float tile[64][33];
        const float* src = Wo + (size_t)l * CHN * CIN;
        #pragma unroll
        for (int p = 0; p < 8; ++p) {
            int row = p * 8 + (tid >> 5);       // c offset
            int col = tid & 31;                 // o offset
            tile[row][col] = src[(size_t)(c0 + row) * CIN + o0 + col];
        }
        __syncthreads();
        ushort* dst = WoT + (size_t)l * CIN * CHN;
        #pragma unroll
        for (int p = 0; p < 8; ++p) {
            int o = p * 4 + (tid >> 6);
            int c = tid & 63;
            dst[(size_t)(o0 + o) * CHN + c0 + c] = f2bu(tile[c][o]);
        }
        return;
    }
    // ---- MFMA projection part: 32 rows x 256 cols, K=128 ----
    {
        const int idx = bid - (NSEG * NH + 48);
        const int z = idx / 144;                 // 0:q 1:k 2:v
        const int rem = idx - z * 144;
        const int s = rem >> 4;                  // 0..8
        const int n0 = (rem & 15) * 32;
        const int l = (s == 0) ? 0 : ((s < 4) ? 1 : 2);
        const float* x = (z == 0) ? q : (z == 1) ? k : v;
        const float* W = ((z == 0) ? Wq : (z == 1) ? Wk : Wv) + (size_t)l * CIN * CHN;
        const float* bias = (z == 0) ? bq : (z == 1) ? bk : bv;
        const int lane = tid & 63, w = tid >> 6;
        const int wr = w >> 1, wc = w & 1;
        const int r = lane & 15, kg = lane >> 4;
        const int arow = n0 + 16 * wr + r;
        const float* xrow = x + ((size_t)arow * SDIM + s) * CIN;
        f32x4 acc[8] = {};
        #pragma unroll
        for (int ks = 0; ks < 4; ++ks) {
            const int k0 = ks * 32 + kg * 8;
            float4 x0 = *(const float4*)(xrow + k0);
            float4 x1 = *(const float4*)(xrow + k0 + 4);
            bf16x8 a;
            a[0] = f2bu(x0.x); a[1] = f2bu(x0.y); a[2] = f2bu(x0.z); a[3] = f2bu(x0.w);
            a[4] = f2bu(x1.x); a[5] = f2bu(x1.y); a[6] = f2bu(x1.z); a[7] = f2bu(x1.w);
            #pragma unroll
            for (int j = 0; j < 8; ++j) {
                const int o = 128 * wc + 16 * j + r;
                const float* wp = W + (size_t)k0 * CHN + o;
                bf16x8 bf;
                #pragma unroll
                for (int jj = 0; jj < 8; ++jj) bf[jj] = f2bu(wp[(size_t)jj * CHN]);
                acc[j] = __builtin_amdgcn_mfma_f32_16x16x32_bf16(a, bf, acc[j], 0, 0, 0);
            }
        }
        const float sc = (z == 0) ? SCALE : 1.0f;
        #pragma unroll
        for (int j = 0; j < 8; ++j) {
            const int o = 128 * wc + 16 * j + r;
            const float bb = (s == 0) ? bias[o] : 0.f;
            const int h = o >> 5, dj = o & 31;
            const int f = s * DH + dj;
            if (z < 2) {
                ushort* dst = (z == 0) ? qhB : khB;
                #pragma unroll
                for (int p = 0; p < 4; ++p) {
                    int row = n0 + 16 * wr + kg * 4 + p;
                    dst[((size_t)h * NATOM + row) * FDIM + f] = f2bu((acc[j][p] + bb) * sc);
                }
            } else {
                ushort* dst = vhT + ((size_t)h * FDIM + f) * NATOM;
                #pragma unroll
                for (int p = 0; p < 4; ++p) {
                    int row = n0 + 16 * wr + kg * 4 + p;
                    dst[row] = f2bu(acc[j][p] + bb);
                }
            }
        }
    }
}

// ---------------- K2: MFMA scores: scoresA[h][n][m] = dot(qhB[h,n,:], khB[h,m,:]) ----------------
__global__ void __launch_bounds__(256) gemm_scores_mfma(const ushort* __restrict__ qhB,
                                                        const ushort* __restrict__ khB,
                                                        float* __restrict__ scoresA) {
    const int h = blockIdx.z;
    const int m0 = blockIdx.x * 64;
    const int n0 = blockIdx.y * 64;
    const int tid = threadIdx.x;
    const int lane = tid & 63, w = tid >> 6;
    const int wr = w >> 1, wc = w & 1;
    const int r = lane & 15, kg = lane >> 4;
    const ushort* A = qhB + (size_t)h * NATOM * FDIM;
    const ushort* B = khB + (size_t)h * NATOM * FDIM;
    const int ar = n0 + 32 * wr + r;
    const int br = m0 + 32 * wc + r;
    f32x4 acc00 = {}, acc01 = {}, acc10 = {}, acc11 = {};
    #pragma unroll
    for (int ks = 0; ks < FDIM / 32; ++ks) {
        const int k0 = ks * 32 + kg * 8;
        bf16x8 a0 = *(const bf16x8*)(A + (size_t)ar * FDIM + k0);
        bf16x8 a1 = *(const bf16x8*)(A + (size_t)(ar + 16) * FDIM + k0);
        bf16x8 b0 = *(const bf16x8*)(B + (size_t)br * FDIM + k0);
        bf16x8 b1 = *(const bf16x8*)(B + (size_t)(br + 16) * FDIM + k0);
        acc00 = __builtin_amdgcn_mfma_f32_16x16x32_bf16(a0, b0, acc00, 0, 0, 0);
        acc01 = __builtin_amdgcn_mfma_f32_16x16x32_bf16(a0, b1, acc01, 0, 0, 0);
        acc10 = __builtin_amdgcn_mfma_f32_16x16x32_bf16(a1, b0, acc10, 0, 0, 0);
        acc11 = __builtin_amdgcn_mfma_f32_16x16x32_bf16(a1, b1, acc11, 0, 0, 0);
    }
    #define STORE_SC(ACC, I, J) { \
        int row = n0 + 32 * wr + (I) * 16 + kg * 4; \
        int col = m0 + 32 * wc + (J) * 16 + r; \
        float* dst = scoresA + ((size_t)h * NATOM + row) * NATOM + col; \
        dst[0] = ACC[0]; dst[NATOM] = ACC[1]; dst[2 * NATOM] = ACC[2]; dst[3 * NATOM] = ACC[3]; }
    STORE_SC(acc00, 0, 0) STORE_SC(acc01, 0, 1) STORE_SC(acc10, 1, 0) STORE_SC(acc11, 1, 1)
    #undef STORE_SC
}

// ---------------- K3: wave-parallel collapsed segmented softmax (fp32 scores -> bf16 attn) ----------------
#define SMW_RPW 4
__global__ void __launch_bounds__(256) softmax_agg3(const float* __restrict__ scoresA,
                                                    ushort* __restrict__ attnB,
                                                    const float* __restrict__ E1,
                                                    const float* __restrict__ E2) {
    const int h = blockIdx.y;
    const int n0 = blockIdx.x * (4 * SMW_RPW);
    __shared__ float E1s[NSEG][NATOM];   // 32 KB
    __shared__ float E2s[NSEG][NATOM];   // 32 KB
    const int tid = threadIdx.x;
    const float* e1g = E1 + (size_t)h * NSEG * NATOM;
    const float* e2g = E2 + (size_t)h * NSEG * NATOM;
    for (int i = tid * 4; i < NSEG * NATOM; i += 1024) {
        *(float4*)&((float*)E1s)[i] = *(const float4*)&e1g[i];
        *(float4*)&((float*)E2s)[i] = *(const float4*)&e2g[i];
    }
    __syncthreads();
    const int lane = tid & 63, wid = tid >> 6;
    const int m0 = lane * 8;
    for (int rr = 0; rr < SMW_RPW; ++rr) {
        const int row = n0 + wid * SMW_RPW + rr;
        const float* srow = scoresA + ((size_t)h * NATOM + row) * NATOM;
        float4 sa = *(const float4*)(srow + m0);
        float4 sb = *(const float4*)(srow + m0 + 4);
        float s[8] = {sa.x, sa.y, sa.z, sa.w, sb.x, sb.y, sb.z, sb.w};
        float mx = fmaxf(fmaxf(fmaxf(s[0], s[1]), fmaxf(s[2], s[3])),
                         fmaxf(fmaxf(s[4], s[5]), fmaxf(s[6], s[7])));
        #pragma unroll
        for (int off = 32; off; off >>= 1) mx = fmaxf(mx, __shfl_xor(mx, off, 64));
        float es[8];
        #pragma unroll
        for (int j = 0; j < 8; ++j) es[j] = __expf(s[j] - mx);
        float D[NSEG];
        #pragma unroll
        for (int g = 0; g < NSEG; ++g) {
            float4 p = *(const float4*)&E1s[g][m0];
            float4 p2 = *(const float4*)&E1s[g][m0 + 4];
            D[g] = es[0] * p.x + es[1] * p.y + es[2] * p.z + es[3] * p.w
                 + es[4] * p2.x + es[5] * p2.y + es[6] * p2.z + es[7] * p2.w;
        }
        #pragma unroll
        for (int g = 0; g < NSEG; ++g) {
            float vv = D[g];
            #pragma unroll
            for (int off = 32; off; off >>= 1) vv += __shfl_xor(vv, off, 64);
            D[g] = vv;
        }
        float w[8] = {};
        #pragma unroll
        for (int g = 0; g < NSEG; ++g) {
            float iv = 1.0f / (D[g] + 1e-30f);
            float4 p = *(const float4*)&E2s[g][m0];
            float4 p2 = *(const float4*)&E2s[g][m0 + 4];
            w[0] += iv * p.x;  w[1] += iv * p.y;  w[2] += iv * p.z;  w[3] += iv * p.w;
            w[4] += iv * p2.x; w[5] += iv * p2.y; w[6] += iv * p2.z; w[7] += iv * p2.w;
        }
        ushort* arow = attnB + ((size_t)h * NATOM + row) * NATOM;
        short8 ov;
        #pragma unroll
        for (int j = 0; j < 8; ++j) ov[j] = (short)f2bu(es[j] * w[j]);
        *(short8*)(arow + m0) = ov;
    }
}

// ---------------- K4: MFMA out: attnOut[n][s][h*32+dj] = sum_m attnB[h,n,m]*vhT[h,f,m] ----------------
__global__ void __launch_bounds__(256) gemm_out_mfma(const ushort* __restrict__ attnB,
                                                     const ushort* __restrict__ vhT,
                                                     float* __restrict__ attnOut) {
    const int h = blockIdx.z;
    const int f0 = blockIdx.x * 64;
    const int n0 = blockIdx.y * 64;
    const int tid = threadIdx.x;
    const int lane = tid & 63, w = tid >> 6;
    const int wr = w >> 1, wc = w & 1;
    const int r = lane & 15, kg = lane >> 4;
    const ushort* A = attnB + (size_t)h * NATOM * NATOM;
    const ushort* B = vhT + (size_t)h * FDIM * NATOM;
    const int ar = n0 + 32 * wr + r;
    const int br = f0 + 32 * wc + r;
    const bool b0ok = (f0 + 32 * wc) < FDIM;
    const bool b1ok = (f0 + 32 * wc + 16) < FDIM;
    f32x4 acc00 = {}, acc01 = {}, acc10 = {}, acc11 = {};
    const bf16x8 bz = {};
    #pragma unroll 4
    for (int ks = 0; ks < NATOM / 32; ++ks) {
        const int k0 = ks * 32 + kg * 8;
        bf16x8 a0 = *(const bf16x8*)(A + (size_t)ar * NATOM + k0);
        bf16x8 a1 = *(const bf16x8*)(A + (size_t)(ar + 16) * NATOM + k0);
        bf16x8 b0 = b0ok ? *(const bf16x8*)(B + (size_t)br * NATOM + k0) : bz;
        bf16x8 b1 = b1ok ? *(const bf16x8*)(B + (size_t)(br + 16) * NATOM + k0) : bz;
        acc00 = __builtin_amdgcn_mfma_f32_16x16x32_bf16(a0, b0, acc00, 0, 0, 0);
        acc01 = __builtin_amdgcn_mfma_f32_16x16x32_bf16(a0, b1, acc01, 0, 0, 0);
        acc10 = __builtin_amdgcn_mfma_f32_16x16x32_bf16(a1, b0, acc10, 0, 0, 0);
        acc11 = __builtin_amdgcn_mfma_f32_16x16x32_bf16(a1, b1, acc11, 0, 0, 0);
    }
    #define STORE_OUT(ACC, I, J) { \
        int row = n0 + 32 * wr + (I) * 16 + kg * 4; \
        int f = f0 + 32 * wc + (J) * 16 + r; \
        if (f < FDIM) { \
            int s = f >> 5, dj = f & 31; \
            float* dst = attnOut + ((size_t)row * SDIM + s) * CHN + h * DH + dj; \
            dst[0] = ACC[0]; dst[SDIM * CHN] = ACC[1]; dst[2 * SDIM * CHN] = ACC[2]; dst[3 * SDIM * CHN] = ACC[3]; } }
    STORE_OUT(acc00, 0, 0) STORE_OUT(acc01, 0, 1) STORE_OUT(acc10, 1, 0) STORE_OUT(acc11, 1, 1)
    #undef STORE_OUT
}

// ---------------- K5: equivariant layernorm -> bf16 normalized ----------------
__global__ void __launch_bounds__(256) eqln_bf16(const float* __restrict__ xin,
                                                 const float* __restrict__ gamma,
                                                 const float* __restrict__ beta,
                                                 ushort* __restrict__ outn) {
    const int n = blockIdx.x;
    const int c = threadIdx.x;
    __shared__ float red[4];
    float xv[SDIM];
    #pragma unroll
    for (int s = 0; s < SDIM; ++s) xv[s] = xin[((size_t)n * SDIM + s) * CHN + c];
    float mu = blockReduceSum(xv[0], red) * (1.0f / CHN);
    float dv = xv[0] - mu;
    float var = blockReduceSum(dv * dv, red) * (1.0f / CHN);
    float y0 = dv / sqrtf(var + EPS) * gamma[c] + beta[c];
    outn[(size_t)n * SDIM * CHN + c] = f2bu(y0);
    float n2 = (xv[1] * xv[1] + xv[2] * xv[2] + xv[3] * xv[3]) * (1.0f / 3.0f);
    float ms = blockReduceSum(n2, red) * (1.0f / CHN);
    float inv1 = 1.0f / sqrtf(ms + EPS);
    #pragma unroll
    for (int s = 1; s < 4; ++s)
        outn[((size_t)n * SDIM + s) * CHN + c] = f2bu(xv[s] * inv1 * gamma[CHN + c]);
    float n22 = (xv[4] * xv[4] + xv[5] * xv[5] + xv[6] * xv[6] + xv[7] * xv[7] + xv[8] * xv[8]) * (1.0f / 5.0f);
    float ms2 = blockReduceSum(n22, red) * (1.0f / CHN);
    float inv2 = 1.0f / sqrtf(ms2 + EPS);
    #pragma unroll
    for (int s = 4; s < SDIM; ++s)
        outn[((size_t)n * SDIM + s) * CHN + c] = f2bu(xv[s] * inv2 * gamma[2 * CHN + c]);
}

// ---------------- K6: MFMA final projection ----------------
__global__ void __launch_bounds__(256) so3out_mfma(const ushort* __restrict__ normedB,
                                                   const ushort* __restrict__ WoT,
                                                   const float* __restrict__ bo,
                                                   float* __restrict__ out) {
    const int s = blockIdx.y;
    const int n0 = blockIdx.x * 64;
    const int l = (s == 0) ? 0 : ((s < 4) ? 1 : 2);
    const int tid = threadIdx.x;
    const int lane = tid & 63, w = tid >> 6;
    const int wr = w >> 1, wc = w & 1;
    const int r = lane & 15, kg = lane >> 4;
    const ushort* B = WoT + (size_t)l * CIN * CHN;
    const int ar = n0 + 32 * wr + r;
    const int bc = 64 * wc;
    f32x4 acc[2][4] = {};
    #pragma unroll
    for (int ks = 0; ks < CHN / 32; ++ks) {
        const int k0 = ks * 32 + kg * 8;
        bf16x8 a0 = *(const bf16x8*)(normedB + ((size_t)ar * SDIM + s) * CHN + k0);
        bf16x8 a1 = *(const bf16x8*)(normedB + ((size_t)(ar + 16) * SDIM + s) * CHN + k0);
        bf16x8 b[4];
        #pragma unroll
        for (int j = 0; j < 4; ++j)
            b[j] = *(const bf16x8*)(B + (size_t)(bc + 16 * j + r) * CHN + k0);
        #pragma unroll
        for (int j = 0; j < 4; ++j) {
            acc[0][j] = __builtin_amdgcn_mfma_f32_16x16x32_bf16(a0, b[j], acc[0][j], 0, 0, 0);
            acc[1][j] = __builtin_amdgcn_mfma_f32_16x16x32_bf16(a1, b[j], acc[1][j], 0, 0, 0);
        }
    }
    #pragma unroll
    for (int i = 0; i < 2; ++i) {
        #pragma unroll
        for (int j = 0; j < 4; ++j) {
            int n = n0 + 32 * wr + 16 * i + kg * 4;
            int o = bc + 16 * j + r;
            float badd = (s == 0) ? bo[o] : 0.f;
            float* dst = out + ((size_t)n * SDIM + s) * CIN + o;
            dst[0] = acc[i][j][0] + badd;
            dst[SDIM * CIN] = acc[i][j][1] + badd;
            dst[2 * SDIM * CIN] = acc[i][j][2] + badd;
            dst[3 * SDIM * CIN] = acc[i][j][3] + badd;
        }
    }
}

extern "C" void kernel_launch(void* const* d_in, const int* in_sizes, int n_in,
                              void* d_out, int out_size, void* d_ws, size_t ws_size,
                              hipStream_t stream) {
    const float* q = (const float*)d_in[0];
    const float* k = (const float*)d_in[1];
    const float* v = (const float*)d_in[2];
    const float* envelope = (const float*)d_in[3];
    const float* attn_bias = (const float*)d_in[4];
    const int* atom_index = (const int*)d_in[5];
    const int* batch_index = (const int*)d_in[6];
    const int* edge_map = (const int*)d_in[7];
    const float* Wq = (const float*)d_in[8];
    const float* bq = (const float*)d_in[9];
    const float* Wk = (const float*)d_in[10];
    const float* bk = (const float*)d_in[11];
    const float* Wv = (const float*)d_in[12];
    const float* bv = (const float*)d_in[13];
    const float* gamma = (const float*)d_in[14];
    const float* beta = (const float*)d_in[15];
    const float* Wo = (const float*)d_in[16];
    const float* bo = (const float*)d_in[17];
    float* out = (float*)d_out;

    const size_t SZ_HNF = (size_t)NH * NATOM * FDIM;      // 1,179,648 elems
    const size_t SZ_HNN = (size_t)NH * NATOM * NATOM;     // 2,097,152 elems
    const size_t SZ_TAB = (size_t)NH * NSEG * NATOM;      // 65,536 elems
    const size_t SZ_WOT = (size_t)3 * CIN * CHN;          // 98,304 elems

    char* wsb = (char*)d_ws;
    ushort* qhB = (ushort*)wsb;                                         // 2 * SZ_HNF bytes
    ushort* khB = qhB + SZ_HNF;
    ushort* vhT = khB + SZ_HNF;                                         // [h][f][n]
    float* scoresA = (float*)(vhT + SZ_HNF);                            // 4 * SZ_HNN bytes
    ushort* attnB = (ushort*)(scoresA + SZ_HNN);                        // 2 * SZ_HNN bytes
    float* E1 = (float*)(attnB + SZ_HNN);
    float* E2 = E1 + SZ_TAB;
    ushort* WoT = (ushort*)(E2 + SZ_TAB);                               // 2 * SZ_WOT bytes
    float* attnOut = scoresA;                 // reuse: scoresA dead after softmax
    ushort* normedB = qhB;                    // reuse: qhB dead after gemm_scores

    size_t needed = 2 * 3 * SZ_HNF + 4 * SZ_HNN + 2 * SZ_HNN + 4 * 2 * SZ_TAB + 2 * SZ_WOT + 256;
    if (ws_size < needed) return;

    stage1<<<NSEG * NH + 48 + 432, 256, 0, stream>>>(
        batch_index, atom_index, edge_map, envelope, attn_bias, E1, E2,
        q, k, v, Wq, Wk, Wv, bq, bk, bv, qhB, khB, vhT, Wo, WoT);
    gemm_scores_mfma<<<dim3(NATOM / 64, NATOM / 64, NH), 256, 0, stream>>>(qhB, khB, scoresA);
    softmax_agg3<<<dim3(NATOM / (4 * SMW_RPW), NH), 256, 0, stream>>>(scoresA, attnB, E1, E2);
    gemm_out_mfma<<<dim3((FDIM + 63) / 64, NATOM / 64, NH), 256, 0, stream>>>(attnB, vhT, attnOut);
    eqln_bf16<<<NATOM, 256, 0, stream>>>(attnOut, gamma, beta, normedB);
    so3out_mfma<<<dim3(NATOM / 64, SDIM), 256, 0, stream>>>(normedB, WoT, bo, out);
}

// Round 8
// 74.718 us; speedup vs baseline: 1.6201x; 1.0457x over previous
//
#include <hip/hip_runtime.h>
#include <hip/hip_bf16.h>
#include <math.h>

#define NH 8
#define SDIM 9
#define NSEG 16
#define NATOM 512
#define NEDGE 8192
#define CIN 128
#define CHN 256
#define DH 32
#define FDIM 288            // SDIM*DH
#define EPS 1e-7f
#define SCALE 0.10206207261596577f   // sqrt(32/3)/32

typedef __attribute__((ext_vector_type(8))) short bf16x8;
typedef __attribute__((ext_vector_type(8))) short short8;
typedef __attribute__((ext_vector_type(4))) float f32x4;

// ---------------- helpers ----------------
__device__ inline float blockReduceMax(float v, float* red) {
    #pragma unroll
    for (int off = 32; off; off >>= 1) v = fmaxf(v, __shfl_xor(v, off, 64));
    int lane = threadIdx.x & 63, wid = threadIdx.x >> 6;
    if (lane == 0) red[wid] = v;
    __syncthreads();
    v = fmaxf(fmaxf(red[0], red[1]), fmaxf(red[2], red[3]));
    __syncthreads();
    return v;
}
__device__ inline int lower_bound_batch(const int* __restrict__ b, int val) {
    int lo = 0, hi = NEDGE;
    while (lo < hi) {
        int mid = (lo + hi) >> 1;
        if (b[mid] < val) lo = mid + 1; else hi = mid;
    }
    return lo;
}
__device__ inline ushort f2bu(float x) {
    __hip_bfloat16 b = __float2bfloat16(x);
    return *(ushort*)&b;
}

// ---------------- K1: fused stage1: seg tables + WoT + MFMA qkv projections + stats zero ----------------
// blocks [0,128): E1/E2 seg tables; [128,176): WoT; [176,608): qkv proj; 608: zero stats
__global__ void __launch_bounds__(256) stage1(const int* __restrict__ batch,
                                              const int* __restrict__ am, const int* __restrict__ emap,
                                              const float* __restrict__ envelope,
                                              const float* __restrict__ attn_bias,
                                              float* __restrict__ E1, float* __restrict__ E2,
                                              const float* __restrict__ q, const float* __restrict__ k,
                                              const float* __restrict__ v,
                                              const float* __restrict__ Wq, const float* __restrict__ Wk,
                                              const float* __restrict__ Wv,
                                              const float* __restrict__ bq, const float* __restrict__ bk,
                                              const float* __restrict__ bv,
                                              ushort* __restrict__ qhB,
                                              ushort* __restrict__ khB,
                                              ushort* __restrict__ vhT,
                                              const float* __restrict__ Wo,
                                              ushort* __restrict__ WoT,
                                              float* __restrict__ stats) {
    const int bid = blockIdx.x;
    const int tid = threadIdx.x;
    if (bid < NSEG * NH) {
        // ---- segment table part ----
        const int seg = bid & (NSEG - 1), h = bid >> 4;
        __shared__ float e1[NATOM];
        __shared__ float e2[NATOM];
        __shared__ float red[4];
        e1[tid] = 0.f; e1[tid + 256] = 0.f;
        e2[tid] = 0.f; e2[tid + 256] = 0.f;
        const float* bh = attn_bias + (size_t)h * NEDGE;
        float mv = -1e30f;
        for (int e = tid; e < NEDGE; e += 256) mv = fmaxf(mv, bh[e]);
        const float mb = blockReduceMax(mv, red);   // barrier inside covers e1/e2 init
        const int st = lower_bound_batch(batch, seg);
        const int en = lower_bound_batch(batch, seg + 1);
        for (int e = st + tid; e < en; e += 256) {
            int m = am[e], em = emap[e];
            float ev = envelope[em];
            float eb = __expf(bh[em] - mb);
            atomicAdd(&e1[m], ev * eb);
            atomicAdd(&e2[m], ev * ev * eb);
        }
        __syncthreads();
        size_t base = ((size_t)h * NSEG + seg) * NATOM;
        E1[base + tid] = e1[tid]; E1[base + tid + 256] = e1[tid + 256];
        E2[base + tid] = e2[tid]; E2[base + tid + 256] = e2[tid + 256];
        return;
    }
    if (bid < NSEG * NH + 48) {
        // ---- WoT transpose: WoT[l][o][c] = bf16(Wo[l][c][o]) ----
        const int t = bid - NSEG * NH;
        const int l = t / 16;
        const int cb = (t & 15) >> 2, ob = t & 3;
        const int c0 = cb * 64, o0 = ob * 32;
        __shared__ float tile[64][33];
        const float* src = Wo + (size_t)l * CHN * CIN;
        #pragma unroll
        for (int p = 0; p < 8; ++p) {
            int row = p * 8 + (tid >> 5);
            int col = tid & 31;
            tile[row][col] = src[(size_t)(c0 + row) * CIN + o0 + col];
        }
        __syncthreads();
        ushort* dst = WoT + (size_t)l * CIN * CHN;
        #pragma unroll
        for (int p = 0; p < 8; ++p) {
            int o = p * 4 + (tid >> 6);
            int c = tid & 63;
            dst[(size_t)(o0 + o) * CHN + c0 + c] = f2bu(tile[c][o]);
        }
        return;
    }
    if (bid < NSEG * NH + 48 + 432) {
        // ---- MFMA projection part: 32 rows x 256 cols, K=128 ----
        const int idx = bid - (NSEG * NH + 48);
        const int z = idx / 144;                 // 0:q 1:k 2:v
        const int rem = idx - z * 144;
        const int s = rem >> 4;                  // 0..8
        const int n0 = (rem & 15) * 32;
        const int l = (s == 0) ? 0 : ((s < 4) ? 1 : 2);
        const float* x = (z == 0) ? q : (z == 1) ? k : v;
        const float* W = ((z == 0) ? Wq : (z == 1) ? Wk : Wv) + (size_t)l * CIN * CHN;
        const float* bias = (z == 0) ? bq : (z == 1) ? bk : bv;
        const int lane = tid & 63, w = tid >> 6;
        const int wr = w >> 1, wc = w & 1;
        const int r = lane & 15, kg = lane >> 4;
        const int arow = n0 + 16 * wr + r;
        const float* xrow = x + ((size_t)arow * SDIM + s) * CIN;
        f32x4 acc[8] = {};
        #pragma unroll
        for (int ks = 0; ks < 4; ++ks) {
            const int k0 = ks * 32 + kg * 8;
            float4 x0 = *(const float4*)(xrow + k0);
            float4 x1 = *(const float4*)(xrow + k0 + 4);
            bf16x8 a;
            a[0] = f2bu(x0.x); a[1] = f2bu(x0.y); a[2] = f2bu(x0.z); a[3] = f2bu(x0.w);
            a[4] = f2bu(x1.x); a[5] = f2bu(x1.y); a[6] = f2bu(x1.z); a[7] = f2bu(x1.w);
            #pragma unroll
            for (int j = 0; j < 8; ++j) {
                const int o = 128 * wc + 16 * j + r;
                const float* wp = W + (size_t)k0 * CHN + o;
                bf16x8 bf;
                #pragma unroll
                for (int jj = 0; jj < 8; ++jj) bf[jj] = f2bu(wp[(size_t)jj * CHN]);
                acc[j] = __builtin_amdgcn_mfma_f32_16x16x32_bf16(a, bf, acc[j], 0, 0, 0);
            }
        }
        const float sc = (z == 0) ? SCALE : 1.0f;
        #pragma unroll
        for (int j = 0; j < 8; ++j) {
            const int o = 128 * wc + 16 * j + r;
            const float bb = (s == 0) ? bias[o] : 0.f;
            const int h = o >> 5, dj = o & 31;
            const int f = s * DH + dj;
            if (z < 2) {
                ushort* dst = (z == 0) ? qhB : khB;
                #pragma unroll
                for (int p = 0; p < 4; ++p) {
                    int row = n0 + 16 * wr + kg * 4 + p;
                    dst[((size_t)h * NATOM + row) * FDIM + f] = f2bu((acc[j][p] + bb) * sc);
                }
            } else {
                ushort* dst = vhT + ((size_t)h * FDIM + f) * NATOM;
                #pragma unroll
                for (int p = 0; p < 4; ++p) {
                    int row = n0 + 16 * wr + kg * 4 + p;
                    dst[row] = f2bu(acc[j][p] + bb);
                }
            }
        }
        return;
    }
    // ---- zero stats buffer: 512*4 floats ----
    {
        float4 z4 = {0.f, 0.f, 0.f, 0.f};
        float4* sp = (float4*)stats;
        sp[tid] = z4;
        sp[tid + 256] = z4;
    }
}

// ---------------- K2: fused scores GEMM + collapsed segmented softmax -> bf16 attnB ----------------
// block: 16 rows (one head), 4 waves x 128 cols. attn[n][m] = es[m] * sum_g E2[g][m]*invD[n][g],
// D[n][g] = sum_m es[m]*E1[g][m], es = exp(s - rowmax).
__global__ void __launch_bounds__(256) attn_fused(const ushort* __restrict__ qhB,
                                                  const ushort* __restrict__ khB,
                                                  const float* __restrict__ E1,
                                                  const float* __restrict__ E2,
                                                  ushort* __restrict__ attnB) {
    const int h = blockIdx.y;
    const int n0 = blockIdx.x * 16;
    __shared__ float E1s[NSEG][NATOM];   // 32 KB (reused as bf16 store buffer at the end)
    __shared__ float E2s[NSEG][NATOM];   // 32 KB
    __shared__ float rowmax[4][16];
    __shared__ float Dpart[4][16][NSEG]; // 4 KB
    __shared__ float invDs[16][NSEG];    // 1 KB
    const int tid = threadIdx.x;
    const int lane = tid & 63, w = tid >> 6;
    const int r = lane & 15, kg = lane >> 4;
    // stage E tables (coalesced)
    {
        const float* e1g = E1 + (size_t)h * NSEG * NATOM;
        const float* e2g = E2 + (size_t)h * NSEG * NATOM;
        for (int i = tid * 4; i < NSEG * NATOM; i += 1024) {
            *(float4*)&((float*)E1s)[i] = *(const float4*)&e1g[i];
            *(float4*)&((float*)E2s)[i] = *(const float4*)&e2g[i];
        }
    }
    // ---- GEMM: rows n0..n0+15, this wave's cols [w*128, w*128+128) ----
    const ushort* A = qhB + (size_t)h * NATOM * FDIM;
    const ushort* B = khB + (size_t)h * NATOM * FDIM;
    const int ar = n0 + r;
    f32x4 acc[8] = {};
    #pragma unroll
    for (int ks = 0; ks < FDIM / 32; ++ks) {
        const int k0 = ks * 32 + kg * 8;
        bf16x8 a = *(const bf16x8*)(A + (size_t)ar * FDIM + k0);
        #pragma unroll
        for (int j = 0; j < 8; ++j) {
            const int bcol = w * 128 + 16 * j + r;
            bf16x8 b = *(const bf16x8*)(B + (size_t)bcol * FDIM + k0);
            acc[j] = __builtin_amdgcn_mfma_f32_16x16x32_bf16(a, b, acc[j], 0, 0, 0);
        }
    }
    __syncthreads();   // E tables staged; all accs ready
    // ---- row max ----
    float pm[4];
    #pragma unroll
    for (int p = 0; p < 4; ++p) {
        float m = acc[0][p];
        #pragma unroll
        for (int j = 1; j < 8; ++j) m = fmaxf(m, acc[j][p]);
        pm[p] = m;
    }
    #pragma unroll
    for (int mk = 1; mk < 16; mk <<= 1)
        #pragma unroll
        for (int p = 0; p < 4; ++p) pm[p] = fmaxf(pm[p], __shfl_xor(pm[p], mk, 64));
    if (r == 0) {
        #pragma unroll
        for (int p = 0; p < 4; ++p) rowmax[w][kg * 4 + p] = pm[p];
    }
    __syncthreads();
    float mx[4];
    #pragma unroll
    for (int p = 0; p < 4; ++p) {
        int row = kg * 4 + p;
        mx[p] = fmaxf(fmaxf(rowmax[0][row], rowmax[1][row]),
                      fmaxf(rowmax[2][row], rowmax[3][row]));
    }
    // ---- es ----
    float es[8][4];
    #pragma unroll
    for (int j = 0; j < 8; ++j)
        #pragma unroll
        for (int p = 0; p < 4; ++p) es[j][p] = __expf(acc[j][p] - mx[p]);
    // ---- D partials over this wave's cols ----
    float Dp[4][NSEG] = {};
    #pragma unroll
    for (int j = 0; j < 8; ++j) {
        const int col = w * 128 + 16 * j + r;
        #pragma unroll
        for (int g = 0; g < NSEG; ++g) {
            float e1 = E1s[g][col];
            #pragma unroll
            for (int p = 0; p < 4; ++p) Dp[p][g] += es[j][p] * e1;
        }
    }
    #pragma unroll
    for (int mk = 1; mk < 16; mk <<= 1)
        #pragma unroll
        for (int p = 0; p < 4; ++p)
            #pragma unroll
            for (int g = 0; g < NSEG; ++g) Dp[p][g] += __shfl_xor(Dp[p][g], mk, 64);
    if (r == 0) {
        #pragma unroll
        for (int p = 0; p < 4; ++p)
            #pragma unroll
            for (int g = 0; g < NSEG; ++g) Dpart[w][kg * 4 + p][g] = Dp[p][g];
    }
    __syncthreads();
    // one thread per (row,g): combine + invert
    {
        int row = tid >> 4, g = tid & 15;
        float d = Dpart[0][row][g] + Dpart[1][row][g] + Dpart[2][row][g] + Dpart[3][row][g];
        invDs[row][g] = 1.0f / (d + 1e-30f);
    }
    __syncthreads();
    // ---- w and store to LDS (reuse E1s as ushort buffer) ----
    float iv[4][NSEG];
    #pragma unroll
    for (int p = 0; p < 4; ++p)
        #pragma unroll
        for (int g = 0; g < NSEG; ++g) iv[p][g] = invDs[kg * 4 + p][g];
    ushort* sbuf = (ushort*)E1s;   // [16][512]
    #pragma unroll
    for (int j = 0; j < 8; ++j) {
        const int col = w * 128 + 16 * j + r;
        float ww[4] = {};
        #pragma unroll
        for (int g = 0; g < NSEG; ++g) {
            float e2 = E2s[g][col];
            #pragma unroll
            for (int p = 0; p < 4; ++p) ww[p] += e2 * iv[p][g];
        }
        #pragma unroll
        for (int p = 0; p < 4; ++p)
            sbuf[(kg * 4 + p) * NATOM + col] = f2bu(es[j][p] * ww[p]);
    }
    __syncthreads();
    // coalesced copy LDS -> attnB (16 rows x 512 cols, contiguous 16 KB)
    {
        ushort* dst = attnB + ((size_t)h * NATOM + n0) * NATOM;
        for (int i = tid * 8; i < 16 * NATOM; i += 2048)
            *(short8*)(dst + i) = *(short8*)(sbuf + i);
    }
}

// ---------------- K3: MFMA out GEMM (32-col f tiles) + LN stat atomics ----------------
// stats[n] = {S0, Q0, Q1, Q2}
__global__ void __launch_bounds__(256) gemm_out_stats(const ushort* __restrict__ attnB,
                                                      const ushort* __restrict__ vhT,
                                                      float* __restrict__ attnOut,
                                                      float* __restrict__ stats) {
    const int h = blockIdx.z;
    const int fb = blockIdx.x;          // 0..8 == s
    const int n0 = blockIdx.y * 64;
    const int tid = threadIdx.x;
    const int lane = tid & 63, w = tid >> 6;
    const int r = lane & 15, kg = lane >> 4;
    const ushort* A = attnB + (size_t)h * NATOM * NATOM;
    const ushort* B = vhT + (size_t)h * FDIM * NATOM;
    const int ar = n0 + 16 * w + r;
    f32x4 acc[2] = {};
    #pragma unroll 4
    for (int ks = 0; ks < NATOM / 32; ++ks) {
        const int k0 = ks * 32 + kg * 8;
        bf16x8 a = *(const bf16x8*)(A + (size_t)ar * NATOM + k0);
        bf16x8 b0 = *(const bf16x8*)(B + (size_t)(32 * fb + 16 * 0 + r) * NATOM + k0);
        bf16x8 b1 = *(const bf16x8*)(B + (size_t)(32 * fb + 16 * 1 + r) * NATOM + k0);
        acc[0] = __builtin_amdgcn_mfma_f32_16x16x32_bf16(a, b0, acc[0], 0, 0, 0);
        acc[1] = __builtin_amdgcn_mfma_f32_16x16x32_bf16(a, b1, acc[1], 0, 0, 0);
    }
    // store + stat partials
    float sA[4], sB[4];
    #pragma unroll
    for (int p = 0; p < 4; ++p) { sA[p] = 0.f; sB[p] = 0.f; }
    #pragma unroll
    for (int j = 0; j < 2; ++j) {
        const int dj = 16 * j + r;
        #pragma unroll
        for (int p = 0; p < 4; ++p) {
            const int row = n0 + 16 * w + kg * 4 + p;
            float x = acc[j][p];
            attnOut[((size_t)row * SDIM + fb) * CHN + h * DH + dj] = x;
            sA[p] += x;
            sB[p] += x * x;
        }
    }
    #pragma unroll
    for (int mk = 1; mk < 16; mk <<= 1)
        #pragma unroll
        for (int p = 0; p < 4; ++p) {
            sA[p] += __shfl_xor(sA[p], mk, 64);
            sB[p] += __shfl_xor(sB[p], mk, 64);
        }
    if (r == 0) {
        #pragma unroll
        for (int p = 0; p < 4; ++p) {
            const int row = n0 + 16 * w + kg * 4 + p;
            if (fb == 0) {
                atomicAdd(&stats[row * 4 + 0], sA[p]);
                atomicAdd(&stats[row * 4 + 1], sB[p]);
            } else if (fb < 4) {
                atomicAdd(&stats[row * 4 + 2], sB[p]);
            } else {
                atomicAdd(&stats[row * 4 + 3], sB[p]);
            }
        }
    }
}

// ---------------- K4: final projection with fused layernorm (normalize on A-load) ----------------
__global__ void __launch_bounds__(256) so3out_ln(const float* __restrict__ attnOut,
                                                 const float* __restrict__ stats,
                                                 const float* __restrict__ gamma,
                                                 const float* __restrict__ beta,
                                                 const ushort* __restrict__ WoT,
                                                 const float* __restrict__ bo,
                                                 float* __restrict__ out) {
    const int s = blockIdx.y;
    const int n0 = blockIdx.x * 16;
    const int l = (s == 0) ? 0 : ((s < 4) ? 1 : 2);
    const int tid = threadIdx.x;
    const int lane = tid & 63, w = tid >> 6;
    const int r = lane & 15, kg = lane >> 4;
    const int ar = n0 + r;
    // factors for this lane's A-row
    float mu, ivl;
    {
        float s0 = stats[ar * 4 + 0];
        float q0 = stats[ar * 4 + 1];
        float q1 = stats[ar * 4 + 2];
        float q2 = stats[ar * 4 + 3];
        float m0 = s0 * (1.0f / CHN);
        float var = q0 * (1.0f / CHN) - m0 * m0;
        if (s == 0) { mu = m0; ivl = 1.0f / sqrtf(var + EPS); }
        else if (s < 4) { mu = 0.f; ivl = 1.0f / sqrtf(q1 * (1.0f / (3 * CHN)) + EPS); }
        else { mu = 0.f; ivl = 1.0f / sqrtf(q2 * (1.0f / (5 * CHN)) + EPS); }
    }
    const float* xrow = attnOut + ((size_t)ar * SDIM + s) * CHN;
    const float* gl = gamma + l * CHN;
    const ushort* B = WoT + (size_t)l * CIN * CHN;
    f32x4 acc[2] = {};
    #pragma unroll
    for (int ks = 0; ks < CHN / 32; ++ks) {
        const int k0 = ks * 32 + kg * 8;
        float4 x0 = *(const float4*)(xrow + k0);
        float4 x1 = *(const float4*)(xrow + k0 + 4);
        float4 g0 = *(const float4*)(gl + k0);
        float4 g1 = *(const float4*)(gl + k0 + 4);
        float y[8];
        y[0] = (x0.x - mu) * ivl * g0.x; y[1] = (x0.y - mu) * ivl * g0.y;
        y[2] = (x0.z - mu) * ivl * g0.z; y[3] = (x0.w - mu) * ivl * g0.w;
        y[4] = (x1.x - mu) * ivl * g1.x; y[5] = (x1.y - mu) * ivl * g1.y;
        y[6] = (x1.z - mu) * ivl * g1.z; y[7] = (x1.w - mu) * ivl * g1.w;
        if (s == 0) {
            float4 b0 = *(const float4*)(beta + k0);
            float4 b1 = *(const float4*)(beta + k0 + 4);
            y[0] += b0.x; y[1] += b0.y; y[2] += b0.z; y[3] += b0.w;
            y[4] += b1.x; y[5] += b1.y; y[6] += b1.z; y[7] += b1.w;
        }
        bf16x8 a;
        #pragma unroll
        for (int jj = 0; jj < 8; ++jj) a[jj] = f2bu(y[jj]);
        bf16x8 b0f = *(const bf16x8*)(B + (size_t)(32 * w + 16 * 0 + r) * CHN + k0);
        bf16x8 b1f = *(const bf16x8*)(B + (size_t)(32 * w + 16 * 1 + r) * CHN + k0);
        acc[0] = __builtin_amdgcn_mfma_f32_16x16x32_bf16(a, b0f, acc[0], 0, 0, 0);
        acc[1] = __builtin_amdgcn_mfma_f32_16x16x32_bf16(a, b1f, acc[1], 0, 0, 0);
    }
    #pragma unroll
    for (int j = 0; j < 2; ++j) {
        const int o = 32 * w + 16 * j + r;
        const float badd = (s == 0) ? bo[o] : 0.f;
        #pragma unroll
        for (int p = 0; p < 4; ++p) {
            const int n = n0 + kg * 4 + p;
            out[((size_t)n * SDIM + s) * CIN + o] = acc[j][p] + badd;
        }
    }
}

extern "C" void kernel_launch(void* const* d_in, const int* in_sizes, int n_in,
                              void* d_out, int out_size, void* d_ws, size_t ws_size,
                              hipStream_t stream) {
    const float* q = (const float*)d_in[0];
    const float* k = (const float*)d_in[1];
    const float* v = (const float*)d_in[2];
    const float* envelope = (const float*)d_in[3];
    const float* attn_bias = (const float*)d_in[4];
    const int* atom_index = (const int*)d_in[5];
    const int* batch_index = (const int*)d_in[6];
    const int* edge_map = (const int*)d_in[7];
    const float* Wq = (const float*)d_in[8];
    const float* bq = (const float*)d_in[9];
    const float* Wk = (const float*)d_in[10];
    const float* bk = (const float*)d_in[11];
    const float* Wv = (const float*)d_in[12];
    const float* bv = (const float*)d_in[13];
    const float* gamma = (const float*)d_in[14];
    const float* beta = (const float*)d_in[15];
    const float* Wo = (const float*)d_in[16];
    const float* bo = (const float*)d_in[17];
    float* out = (float*)d_out;

    const size_t SZ_HNF = (size_t)NH * NATOM * FDIM;      // 1,179,648
    const size_t SZ_HNN = (size_t)NH * NATOM * NATOM;     // 2,097,152
    const size_t SZ_TAB = (size_t)NH * NSEG * NATOM;      // 65,536
    const size_t SZ_WOT = (size_t)3 * CIN * CHN;          // 98,304
    const size_t SZ_NSC = (size_t)NATOM * SDIM * CHN;     // 1,179,648

    char* wsb = (char*)d_ws;
    ushort* qhB = (ushort*)wsb;
    ushort* khB = qhB + SZ_HNF;
    ushort* vhT = khB + SZ_HNF;                           // [h][f][n]
    ushort* attnB = vhT + SZ_HNF;                         // [h][n][m]
    float* attnOut = (float*)(attnB + SZ_HNN);            // [n][s][c] fp32
    float* E1 = attnOut + SZ_NSC;
    float* E2 = E1 + SZ_TAB;
    ushort* WoT = (ushort*)(E2 + SZ_TAB);                 // [l][o][c]
    float* stats = (float*)(WoT + SZ_WOT);                // [n][4]

    size_t needed = 2 * 3 * SZ_HNF + 2 * SZ_HNN + 4 * SZ_NSC + 4 * 2 * SZ_TAB
                  + 2 * SZ_WOT + 4 * NATOM * 4 + 256;
    if (ws_size < needed) return;

    stage1<<<NSEG * NH + 48 + 432 + 1, 256, 0, stream>>>(
        batch_index, atom_index, edge_map, envelope, attn_bias, E1, E2,
        q, k, v, Wq, Wk, Wv, bq, bk, bv, qhB, khB, vhT, Wo, WoT, stats);
    attn_fused<<<dim3(NATOM / 16, NH), 256, 0, stream>>>(qhB, khB, E1, E2, attnB);
    gemm_out_stats<<<dim3(SDIM, NATOM / 64, NH), 256, 0, stream>>>(attnB, vhT, attnOut, stats);
    so3out_ln<<<dim3(NATOM / 16, SDIM), 256, 0, stream>>>(attnOut, stats, gamma, beta, WoT, bo, out);
}